// Round 7
// baseline (152.512 us; speedup 1.0000x reference)
//
#include <hip/hip_runtime.h>

typedef __attribute__((ext_vector_type(4))) float f32x4;
typedef __attribute__((ext_vector_type(8))) short bfrag; // 8 x bf16 in 4 VGPRs

#define NCH 256
#define BN_EPS 1e-5f

__device__ __forceinline__ unsigned short cvt_bf16(float f){
  unsigned u = __float_as_uint(f);
  u += 0x7FFFu + ((u >> 16) & 1u);           // round-to-nearest-even
  return (unsigned short)(u >> 16);
}
__device__ __forceinline__ float bf16tof(unsigned short h){
  return __uint_as_float(((unsigned)h) << 16);
}
__device__ __forceinline__ void split2(const f32x4 va, const f32x4 vb, bfrag& hi, bfrag& lo){
  #pragma unroll
  for (int e = 0; e < 4; ++e){
    unsigned short h0 = cvt_bf16(va[e]);
    hi[e]   = (short)h0;
    lo[e]   = (short)cvt_bf16(va[e] - bf16tof(h0));
    unsigned short h1b = cvt_bf16(vb[e]);
    hi[4+e] = (short)h1b;
    lo[4+e] = (short)cvt_bf16(vb[e] - bf16tof(h1b));
  }
}

#define GLOAD_LDS16(gp, lp) \
  __builtin_amdgcn_global_load_lds((const __attribute__((address_space(1))) unsigned*)(gp), \
                                   (__attribute__((address_space(3))) unsigned*)(lp), 16, 0, 0)

// ---- K0: pack W1 (hi-only, K 440->448) and W2 (hi-only) into MFMA fragment order;
//      zero gsum ----
__global__ void k_prep(const float* __restrict__ W1, const float* __restrict__ W2,
                       unsigned short* __restrict__ W1p, unsigned short* __restrict__ W2p,
                       float* __restrict__ gsum){
  int t = blockIdx.x * 256 + threadIdx.x;
  if (t < 14 * 8192){
    int e = t & 7, l = (t >> 3) & 63, c = (t >> 9) & 15, s = t >> 13;
    int chan = c * 16 + (l & 15);
    int k = s * 32 + (l >> 4) * 8 + e;
    float v = (k < 440) ? W1[chan * 440 + k] : 0.f;
    W1p[s * 8192 + c * 512 + l * 8 + e] = cvt_bf16(v);
  }
  if (t < 16384){
    int e = t & 7, l = (t >> 3) & 63, c = (t >> 9) & 3, s = t >> 11;
    int chan = c * 16 + (l & 15);
    int k = s * 32 + (l >> 4) * 8 + e;
    W2p[s * 2048 + c * 512 + l * 8 + e] = cvt_bf16(W2[chan * 256 + k]);
  }
  if (t < 512) gsum[t] = 0.f;
}

__device__ __forceinline__ void stage_w(const char* __restrict__ wsrc, char* smem,
                                        int S, int BUF, int w, int l){
  #pragma unroll
  for (int r = 0; r < 4; ++r)
    GLOAD_LDS16(wsrc + S * 16384 + (w * 4 + r) * 1024 + l * 16,
                smem + BUF * 16384 + (w * 4 + r) * 1024);
}

// ---- K1: producer/consumer split. 512 blocks x 512 thr (8 waves).
// waves 0-3 = consumers (32 rows each, MFMA; vm queue = W global_load_lds ONLY)
// waves 4-7 = producers (gather x, split to hi/lo bf16, ds_write into x slots;
//                        vm queue = gathers+mp ONLY -> deep pipeline, no W drag)
__global__ __launch_bounds__(512, 2) void k_gemm1(
    const int* __restrict__ state, const int* __restrict__ counts, const int* __restrict__ mp,
    const float* __restrict__ embed, const float* __restrict__ stab, const float* __restrict__ ctab,
    const unsigned short* __restrict__ W1p, const float* __restrict__ b1,
    unsigned short* __restrict__ h1b, float* __restrict__ gsum)
{
  __shared__ __align__(16) char lds[65536];
  // [0,32768): W double-buffer (16K per step slice)
  // [32768,65536): x double-buffer; slot = [row 128][hi 32sh | lo 32sh] (128B/row), XOR-swizzled

  const int tid = threadIdx.x;
  const int w  = tid >> 6;
  const int l  = tid & 63;
  const char* wsrc = (const char*)W1p;

  if (w >= 4){
    // ================= PRODUCER =================
    const int q  = w - 4;
    const int g  = l & 3;                       // k-slice 0..3 (k = g*8..g*8+7)
    const int rA = q * 32 + (l >> 2);           // local rows (2 per lane)
    const int rB = rA + 16;
    const int gA = blockIdx.x * 128 + rA;
    const int gB = blockIdx.x * 128 + rB;

    const int stA = state[gA] * 32,  stB = state[gB] * 32;
    const int ctA = counts[gA] * 16, ctB = counts[gB] * 16;

    int   mAv[14], mBv[14];
    f32x4 pa[14][2], pb[14][2];

    // mp column for step S (clamped; S=13,g=3 is K-pad -> zeroed at split)
    #define MCOL(S) ((S) == 1 ? (g >= 2 ? g - 2 : 0) \
                              : (4*(S) + g - 6 > 48 ? 48 : 4*(S) + g - 6))

    // prologue: mp(1),mp(2); g(0) from state table; g(1) from counts/embed
    mAv[1] = mp[gA * 49 + MCOL(1)];  mBv[1] = mp[gB * 49 + MCOL(1)];
    mAv[2] = mp[gA * 49 + MCOL(2)];  mBv[2] = mp[gB * 49 + MCOL(2)];
    {
      const float* aA = stab + stA + g * 8;
      const float* aB = stab + stB + g * 8;
      pa[0][0] = *(const f32x4*)aA; pb[0][0] = *(const f32x4*)(aA + 4);
      pa[0][1] = *(const f32x4*)aB; pb[0][1] = *(const f32x4*)(aB + 4);
    }
    {
      const float* aA = (g < 2) ? (ctab + ctA + g * 8) : (embed + ((mAv[1] & 0xFFFFFF) << 3));
      const float* aB = (g < 2) ? (ctab + ctB + g * 8) : (embed + ((mBv[1] & 0xFFFFFF) << 3));
      pa[1][0] = *(const f32x4*)aA; pb[1][0] = *(const f32x4*)(aA + 4);
      pa[1][1] = *(const f32x4*)aB; pb[1][1] = *(const f32x4*)(aB + 4);
    }

    #pragma unroll
    for (int S = 0; S < 14; ++S){
      // issue mp 3 ahead (older than all later gathers -> never dragged)
      if (S <= 10){
        mAv[S+3] = mp[gA * 49 + MCOL(S+3)];
        mBv[S+3] = mp[gB * 49 + MCOL(S+3)];
      }
      // consume g(S) (compiler emits exact vmcnt; g(S+1) stays in flight)
      f32x4 a0 = pa[S][0], b0 = pb[S][0], a1 = pa[S][1], b1r = pb[S][1];
      if (S == 13 && g == 3){
        a0 = (f32x4){0.f,0.f,0.f,0.f}; b0 = a0; a1 = a0; b1r = a0;
      }
      bfrag hi0, lo0, hi1, lo1;
      split2(a0, b0, hi0, lo0);
      split2(a1, b1r, hi1, lo1);
      {
        char* slot = lds + 32768 + (S & 1) * 16384;
        *(bfrag*)(slot + rA*128 + ((g*16)      ^ ((rA & 7) << 4))) = hi0;
        *(bfrag*)(slot + rA*128 + ((64 + g*16) ^ ((rA & 7) << 4))) = lo0;
        *(bfrag*)(slot + rB*128 + ((g*16)      ^ ((rB & 7) << 4))) = hi1;
        *(bfrag*)(slot + rB*128 + ((64 + g*16) ^ ((rB & 7) << 4))) = lo1;
      }
      // issue g(S+2) (uses mp(S+2), issued >=1 step ago; all S+2>=2 -> embed)
      if (S <= 11){
        const float* aA = embed + ((mAv[S+2] & 0xFFFFFF) << 3);
        const float* aB = embed + ((mBv[S+2] & 0xFFFFFF) << 3);
        pa[S+2][0] = *(const f32x4*)aA; pb[S+2][0] = *(const f32x4*)(aA + 4);
        pa[S+2][1] = *(const f32x4*)aB; pb[S+2][1] = *(const f32x4*)(aB + 4);
      }
      // drain own x-slot ds_writes BEFORE the handshake barrier
      __builtin_amdgcn_sched_barrier(0);
      asm volatile("s_waitcnt lgkmcnt(0)" ::: "memory");
      __builtin_amdgcn_sched_barrier(0);
      __builtin_amdgcn_s_barrier();          // [C] slot S ready
      __builtin_amdgcn_s_barrier();          // [E] pacing with consumers
    }
    #undef MCOL
    return;   // producers exit; consumers have no barriers after their loop

  } else {
    // ================= CONSUMER =================
    const int lr = l & 15;
    const int g  = l >> 4;
    const int rowbase = blockIdx.x * 128 + w * 32;
    const int rl0 = w * 32 + lr, rl1 = rl0 + 16;

    f32x4 acc0[16], acc1[16];
    #pragma unroll
    for (int i = 0; i < 16; ++i){ acc0[i] = (f32x4){0.f,0.f,0.f,0.f}; acc1[i] = acc0[i]; }

    stage_w(wsrc, lds, 0, 0, w, l);          // W(0) -> buf0 (consumer queue: W only)

    #pragma unroll
    for (int S = 0; S < 14; ++S){
      if (S < 13) stage_w(wsrc, lds, S + 1, (S + 1) & 1, w, l);

      // drain OWN W(S) quarter BEFORE the barrier -> after barrier, whole W(S)
      // slice (all 4 consumer waves' quarters) is resident.  [r6 bug fix]
      __builtin_amdgcn_sched_barrier(0);
      if (S < 13) asm volatile("s_waitcnt vmcnt(4)" ::: "memory");
      else        asm volatile("s_waitcnt vmcnt(0)" ::: "memory");
      __builtin_amdgcn_sched_barrier(0);
      __builtin_amdgcn_s_barrier();          // [C] x slot S + W(S) ready
      asm volatile("" ::: "memory");         // no LDS read hoists above the barrier
      __builtin_amdgcn_sched_barrier(0);

      const char* slot = lds + 32768 + (S & 1) * 16384;
      const bfrag ahi0 = *(const bfrag*)(slot + rl0*128 + ((g*16)      ^ ((rl0 & 7) << 4)));
      const bfrag alo0 = *(const bfrag*)(slot + rl0*128 + ((64 + g*16) ^ ((rl0 & 7) << 4)));
      const bfrag ahi1 = *(const bfrag*)(slot + rl1*128 + ((g*16)      ^ ((rl1 & 7) << 4)));
      const bfrag alo1 = *(const bfrag*)(slot + rl1*128 + ((64 + g*16) ^ ((rl1 & 7) << 4)));

      const char* base = lds + (S & 1) * 16384 + l * 16;
      #pragma unroll
      for (int c = 0; c < 16; ++c){
        const bfrag bhi = *(const bfrag*)(base + c * 1024);
        acc0[c] = __builtin_amdgcn_mfma_f32_16x16x32_bf16(ahi0, bhi, acc0[c], 0, 0, 0);
        acc0[c] = __builtin_amdgcn_mfma_f32_16x16x32_bf16(alo0, bhi, acc0[c], 0, 0, 0);
        acc1[c] = __builtin_amdgcn_mfma_f32_16x16x32_bf16(ahi1, bhi, acc1[c], 0, 0, 0);
        acc1[c] = __builtin_amdgcn_mfma_f32_16x16x32_bf16(alo1, bhi, acc1[c], 0, 0, 0);
      }
      __builtin_amdgcn_s_barrier();          // [E] slot S free for overwrite at S+2
    }

    // epilogue: bias, h1(bf16) write, stats via shfl + direct atomics (no block barrier)
    #pragma unroll
    for (int c = 0; c < 16; ++c){
      const int j = c * 16 + lr;
      const float bb = b1[j];
      float s = 0.f, qq = 0.f;
      #pragma unroll
      for (int e = 0; e < 4; ++e){
        float h = acc0[c][e] + bb;
        s += h; qq += h * h;
        h1b[(rowbase + g * 4 + e) * NCH + j] = cvt_bf16(h);
      }
      #pragma unroll
      for (int e = 0; e < 4; ++e){
        float h = acc1[c][e] + bb;
        s += h; qq += h * h;
        h1b[(rowbase + 16 + g * 4 + e) * NCH + j] = cvt_bf16(h);
      }
      s  += __shfl_xor(s, 16);  s  += __shfl_xor(s, 32);
      qq += __shfl_xor(qq, 16); qq += __shfl_xor(qq, 32);
      if (g == 0){
        atomicAdd(&gsum[j], s);
        atomicAdd(&gsum[256 + j], qq);
      }
    }
  }
}

// ---- K2: BN(from gsum) + GEMM2 (2-pass MFMA, W2 in LDS) + ReLU + GEMM3 + ReLU + GEMM4 ----
__global__ __launch_bounds__(256, 3) void k_tail(
    const unsigned short* __restrict__ h1b, const float* __restrict__ gsum,
    const float* __restrict__ gamma, const float* __restrict__ beta,
    const unsigned short* __restrict__ W2p,
    const float* __restrict__ b2, const float* __restrict__ W3, const float* __restrict__ b3,
    const float* __restrict__ W4, const float* __restrict__ b4,
    float* __restrict__ out)
{
  __shared__ float ssl[512];
  __shared__ __align__(16) short w2s[16384];   // 32 KiB
  __shared__ float h2l[4][16][65];

  const int tid = threadIdx.x;
  const int w  = tid >> 6;
  const int l  = tid & 63;
  const int lr = l & 15;
  const int g  = l >> 4;
  const int rowbase = blockIdx.x * 128 + w * 32;

  {
    float su = gsum[tid];
    float sq = gsum[256 + tid];
    float mu  = su * (1.f / 65536.f);
    float var = sq * (1.f / 65536.f) - mu * mu;
    float sc  = gamma[tid] * rsqrtf(var + BN_EPS);
    ssl[tid]       = sc;
    ssl[256 + tid] = beta[tid] - mu * sc;
  }
  #pragma unroll
  for (int it = 0; it < 8; ++it)
    GLOAD_LDS16((const char*)W2p + (it * 256 + tid) * 16, (char*)w2s + (it * 256 + tid) * 16);
  __syncthreads();   // drains vmcnt + lgkmcnt

  const float b4v = b4[0];

  #pragma unroll
  for (int t = 0; t < 2; ++t){
    const int rowt = rowbase + t * 16;

    f32x4 acc[4];
    #pragma unroll
    for (int i = 0; i < 4; ++i) acc[i] = (f32x4){0.f, 0.f, 0.f, 0.f};

    #pragma unroll
    for (int s = 0; s < 8; ++s){
      const int kk = s * 32 + g * 8;
      bfrag hv = *(const bfrag*)(h1b + (rowt + lr) * 256 + kk);
      bfrag ahi, alo;
      #pragma unroll
      for (int e = 0; e < 8; ++e){
        float x = fmaf(bf16tof((unsigned short)hv[e]), ssl[kk + e], ssl[256 + kk + e]);
        unsigned short h0 = cvt_bf16(x);
        ahi[e] = (short)h0;
        alo[e] = (short)cvt_bf16(x - bf16tof(h0));
      }
      const char* base = (const char*)w2s + s * 4096 + l * 16;
      #pragma unroll
      for (int c = 0; c < 4; ++c){
        const bfrag bhi = *(const bfrag*)(base + c * 1024);
        acc[c] = __builtin_amdgcn_mfma_f32_16x16x32_bf16(ahi, bhi, acc[c], 0, 0, 0);
        acc[c] = __builtin_amdgcn_mfma_f32_16x16x32_bf16(alo, bhi, acc[c], 0, 0, 0);
      }
    }

    #pragma unroll
    for (int c = 0; c < 4; ++c){
      int j = c * 16 + lr;
      float bb = b2[j];
      #pragma unroll
      for (int e = 0; e < 4; ++e){
        float h = acc[c][e] + bb;
        h2l[w][g * 4 + e][j] = h > 0.f ? h : 0.f;
      }
    }

    float a3[4];
    #pragma unroll
    for (int t3 = 0; t3 < 4; ++t3) a3[t3] = b3[g * 4 + t3];
    #pragma unroll 4
    for (int k = 0; k < 64; ++k){
      float hv = h2l[w][lr][k];
      #pragma unroll
      for (int t3 = 0; t3 < 4; ++t3) a3[t3] += hv * W3[(g * 4 + t3) * 64 + k];
    }

    float p = 0.f;
    #pragma unroll
    for (int t3 = 0; t3 < 4; ++t3){
      float h = a3[t3] > 0.f ? a3[t3] : 0.f;
      p += h * W4[g * 4 + t3];
    }
    p += __shfl_xor(p, 16);
    p += __shfl_xor(p, 32);
    if (l < 16) out[rowt + lr] = p + b4v;
  }
}

extern "C" void kernel_launch(void* const* d_in, const int* in_sizes, int n_in,
                              void* d_out, int out_size, void* d_ws, size_t ws_size,
                              hipStream_t stream){
  const int*   state = (const int*)d_in[0];
  const int*   counts= (const int*)d_in[1];
  const int*   mp    = (const int*)d_in[2];
  const float* embed = (const float*)d_in[3];
  const float* stab  = (const float*)d_in[4];
  const float* ctab  = (const float*)d_in[5];
  const float* W1    = (const float*)d_in[6];
  const float* b1    = (const float*)d_in[7];
  const float* gamma = (const float*)d_in[8];
  const float* beta  = (const float*)d_in[9];
  const float* W2    = (const float*)d_in[10];
  const float* b2    = (const float*)d_in[11];
  const float* W3    = (const float*)d_in[12];
  const float* b3    = (const float*)d_in[13];
  const float* W4    = (const float*)d_in[14];
  const float* b4    = (const float*)d_in[15];
  float* out = (float*)d_out;

  char* ws = (char*)d_ws;
  unsigned short* h1bf = (unsigned short*)(ws);              // 32 MiB
  float* gsum          = (float*)(ws + 33554432);            // 2 KiB (sum|sq)
  unsigned short* W1p  = (unsigned short*)(ws + 33558528);   // 224 KiB
  unsigned short* W2p  = (unsigned short*)(ws + 33787904);   // 32 KiB

  k_prep <<<448, 256, 0, stream>>>(W1, W2, W1p, W2p, gsum);
  k_gemm1<<<512, 512, 0, stream>>>(state, counts, mp, embed, stab, ctab,
                                   W1p, b1, h1bf, gsum);
  k_tail <<<512, 256, 0, stream>>>(h1bf, gsum, gamma, beta, W2p,
                                   b2, W3, b3, W4, b4, out);
}